// Round 16
// baseline (853.141 us; speedup 1.0000x reference)
//
#include <hip/hip_runtime.h>

#define N 4096
#define D 64
#define TCAP 1024
#define TTHRESH 96
#define SNB 256
#define SNT 512
#define S0B 2048
#define S0T 256
#define RPAIRS 6

typedef unsigned long long u64;
#define LO32(k) ((int)(unsigned)((k) & 0xffffffffull))

// ---- persistent device state ----
__device__ float g_C[(size_t)N * (size_t)N];   // 64 MB cost matrix
__device__ float g_tailC[(size_t)TCAP * TCAP]; // 4 MB dense tail matrix
__device__ float4 g_yT[N * 16];                // y transposed: [kc][row] float4 slices (1 MB)
__device__ float g_x2[N], g_y2[N];
__device__ int   g_rowMatch[N];
__device__ int   g_freeRows[2][N];
__device__ int   g_freeCols[2][N];
// per-round row/col min keys, double-buffered by round parity.
// rowMinR/colMin = 1st min; rowMin2/colMin2 = 2nd min (distinct col/row).
// [parity 0] is also round-0's buffer (scan0 writes 1st-min only; 2nd-min
// stays ~0 sentinel -> match(0)'s iter-2 degrades to a no-op).
__device__ u64   g_rowMinR[2][N];
__device__ u64   g_rowMin2[2][N];
__device__ u64   g_colMin[2][N];
__device__ u64   g_colMin2[2][N];
__device__ int   g_nr[2], g_nc[2];
__device__ int   g_done, g_finalCur;

__device__ inline u64 shfl_down_u64(u64 v, int d) {
  unsigned lo = (unsigned)(v & 0xffffffffull);
  unsigned hi = (unsigned)(v >> 32);
  lo = __shfl_down(lo, d, 64);
  hi = __shfl_down(hi, d, 64);
  return ((u64)hi << 32) | (u64)lo;
}

// 512-thread (8-wave) block min-reduce of per-thread best[r], r < rows <= 16.
// Result for row r in s_part[128 + r]. (used by tail path only)
__device__ inline void block_rowmin_reduce8(u64* best, int rows, u64* s_part) {
  const int tid = threadIdx.x;
  const int lane = tid & 63;
  const int wv = tid >> 6;
#pragma unroll
  for (int r = 0; r < 16; ++r) {
    if (r < rows) {
      u64 v = best[r];
#pragma unroll
      for (int d = 32; d > 0; d >>= 1) {
        u64 o = shfl_down_u64(v, d);
        v = (o < v) ? o : v;
      }
      if (lane == 0) s_part[r * 8 + wv] = v;
    }
  }
  __syncthreads();
  if (tid < rows) {
    u64 mn = s_part[tid * 8];
#pragma unroll
    for (int w = 1; w < 8; ++w) {
      u64 o = s_part[tid * 8 + w];
      mn = (o < mn) ? o : mn;
    }
    s_part[128 + tid] = mn;
  }
}

// constant-index float4-array element access (folds to a register after unroll)
__device__ __forceinline__ float f4e(const float4* a, int e) {
  float4 v = a[e >> 2];
  switch (e & 3) {
    case 0: return v.x;
    case 1: return v.y;
    case 2: return v.z;
    default: return v.w;
  }
}

// two-cell atomic top-2 insert: m1 = global min, m2 = global 2nd-min.
// Standard displacement trick; correct for distinct-key streams.
__device__ __forceinline__ void insert2(u64* m1, u64* m2, u64 k) {
  if (k == ~0ull) return;
  u64 old = atomicMin((unsigned long long*)m1, k);
  u64 loser = (k < old) ? old : k;
  if (loser != ~0ull) atomicMin((unsigned long long*)m2, loser);
}

// ================= init: x2/y2 + y-transpose + state reset =================
__global__ void __launch_bounds__(256) k_init(const float* __restrict__ x,
                                              const float* __restrict__ y) {
  const int i = blockIdx.x * 256 + threadIdx.x;  // grid = 16 blocks -> 4096
  // numpy pairwise_sum order for n=64: 8 accumulators, then
  // ((r0+r1)+(r2+r3)) + ((r4+r5)+(r6+r7)). No FMA contraction.
  const float4* xr4 = reinterpret_cast<const float4*>(x + (size_t)i * D);
  const float4* yr4 = reinterpret_cast<const float4*>(y + (size_t)i * D);

  {  // x pass
    float4 xv[16];
#pragma unroll
    for (int k = 0; k < 16; ++k) xv[k] = xr4[k];
    float qx[8];
#pragma unroll
    for (int j = 0; j < 8; ++j) {
      float v = f4e(xv, j);
      qx[j] = __fmul_rn(v, v);
    }
#pragma unroll
    for (int m = 8; m < D; m += 8) {
#pragma unroll
      for (int j = 0; j < 8; ++j) {
        float v = f4e(xv, m + j);
        qx[j] = __fadd_rn(qx[j], __fmul_rn(v, v));
      }
    }
    g_x2[i] = __fadd_rn(__fadd_rn(__fadd_rn(qx[0], qx[1]), __fadd_rn(qx[2], qx[3])),
                        __fadd_rn(__fadd_rn(qx[4], qx[5]), __fadd_rn(qx[6], qx[7])));
  }
  {  // y pass + transpose store
    float4 yv[16];
#pragma unroll
    for (int k = 0; k < 16; ++k) yv[k] = yr4[k];
    float qy[8];
#pragma unroll
    for (int j = 0; j < 8; ++j) {
      float w = f4e(yv, j);
      qy[j] = __fmul_rn(w, w);
    }
#pragma unroll
    for (int m = 8; m < D; m += 8) {
#pragma unroll
      for (int j = 0; j < 8; ++j) {
        float w = f4e(yv, m + j);
        qy[j] = __fadd_rn(qy[j], __fmul_rn(w, w));
      }
    }
    g_y2[i] = __fadd_rn(__fadd_rn(__fadd_rn(qy[0], qy[1]), __fadd_rn(qy[2], qy[3])),
                        __fadd_rn(__fadd_rn(qy[4], qy[5]), __fadd_rn(qy[6], qy[7])));
    // yT[kc][row]: lane-consecutive i -> fully coalesced 16B stores per kc
#pragma unroll
    for (int k = 0; k < 16; ++k) g_yT[(k << 12) + i] = yv[k];
  }

  g_rowMatch[i] = -1;
  g_freeRows[0][i] = i;
  g_freeCols[0][i] = i;
  g_rowMinR[0][i] = ~0ull;
  g_rowMinR[1][i] = ~0ull;
  g_rowMin2[0][i] = ~0ull;
  g_rowMin2[1][i] = ~0ull;
  g_colMin[0][i] = ~0ull;
  g_colMin[1][i] = ~0ull;
  g_colMin2[0][i] = ~0ull;
  g_colMin2[1][i] = ~0ull;
  if (i == 0) {
    g_nr[0] = N; g_nc[0] = N; g_nr[1] = 0; g_nc[1] = 0;
    g_done = 0;
    g_finalCur = ((RPAIRS & 1) ^ 1);  // fallback parity if g_done never fires
  }
}

// ================= round 0: fused cost + C store + row/col minima =================
// Per-thread body IDENTICAL to the proven 138us/124-VGPR kernel (acc[8][4],
// 8 rows, 4 cols/thread, wave-uniform x float4 loads -> SGPRs, yT
// lane-contiguous loads, plain C stores, bare __launch_bounds__). Only the
// BLOCK GEOMETRY changes: 2048 blocks = 512 row-groups x 4 column-quarters,
// 256 threads (4 waves). Rationale: at 124 VGPR an 8-wave block quantizes
// to ONE resident block/CU (21% occupancy, rounds 13-15); 4-wave granules
// let up to 4 blocks/CU co-reside -> ~2x occupancy for the same regalloc.
// Row minima merged across quarter-blocks via atomicMin on g_rowMinR[0]
// (validated r3+); colMin already atomic. Per-(r,c) fmaf chain order:
// kc ascending, x/y/z/w -> bit-exact costs under any column partition.
__global__ void __launch_bounds__(S0T) k_scan0(const float* __restrict__ x,
                                               const float* __restrict__ y) {
  __shared__ u64 s_part[32 + 8];
  const int tid = threadIdx.x;
  const int r0 = (blockIdx.x >> 2) << 3;   // 512 row-groups x 8 rows
  const int qh = blockIdx.x & 3;           // column quarter (1024 cols)

  float x2r[8];
#pragma unroll
  for (int r = 0; r < 8; ++r) x2r[r] = g_x2[r0 + r];
  u64 best[8];
#pragma unroll
  for (int r = 0; r < 8; ++r) best[r] = ~0ull;

  const int c0 = (qh << 10) + tid;  // cols c0 + 256*k, k=0..3
  float acc[8][4];
#pragma unroll
  for (int r = 0; r < 8; ++r)
#pragma unroll
    for (int k = 0; k < 4; ++k) acc[r][k] = 0.0f;

#pragma unroll
  for (int kc = 0; kc < 16; ++kc) {
    const float4* ytk = g_yT + (kc << 12);
    float4 yv0 = ytk[c0];
    float4 yv1 = ytk[c0 + 256];
    float4 yv2 = ytk[c0 + 512];
    float4 yv3 = ytk[c0 + 768];
#pragma unroll
    for (int r = 0; r < 8; ++r) {
      float4 xv = reinterpret_cast<const float4*>(x + (size_t)(r0 + r) * D)[kc];  // wave-uniform -> SGPR
      acc[r][0] = fmaf(xv.x, yv0.x, acc[r][0]);
      acc[r][0] = fmaf(xv.y, yv0.y, acc[r][0]);
      acc[r][0] = fmaf(xv.z, yv0.z, acc[r][0]);
      acc[r][0] = fmaf(xv.w, yv0.w, acc[r][0]);
      acc[r][1] = fmaf(xv.x, yv1.x, acc[r][1]);
      acc[r][1] = fmaf(xv.y, yv1.y, acc[r][1]);
      acc[r][1] = fmaf(xv.z, yv1.z, acc[r][1]);
      acc[r][1] = fmaf(xv.w, yv1.w, acc[r][1]);
      acc[r][2] = fmaf(xv.x, yv2.x, acc[r][2]);
      acc[r][2] = fmaf(xv.y, yv2.y, acc[r][2]);
      acc[r][2] = fmaf(xv.z, yv2.z, acc[r][2]);
      acc[r][2] = fmaf(xv.w, yv2.w, acc[r][2]);
      acc[r][3] = fmaf(xv.x, yv3.x, acc[r][3]);
      acc[r][3] = fmaf(xv.y, yv3.y, acc[r][3]);
      acc[r][3] = fmaf(xv.z, yv3.z, acc[r][3]);
      acc[r][3] = fmaf(xv.w, yv3.w, acc[r][3]);
    }
  }

#pragma unroll
  for (int k = 0; k < 4; ++k) {
    const int c = c0 + (k << 8);
    const float y2j = g_y2[c];
    u64 ckey = ~0ull;
#pragma unroll
    for (int r = 0; r < 8; ++r) {
      float t = __fadd_rn(x2r[r], y2j);
      float sq = __fsub_rn(t, __fmul_rn(2.0f, acc[r][k]));
      sq = fmaxf(sq, 0.0f);
      float cost = __fsqrt_rn(sq);
      g_C[(size_t)(r0 + r) * N + c] = cost;
      u64 cb = ((u64)__float_as_uint(cost)) << 32;
      u64 rk = cb | (unsigned)c;
      best[r] = (rk < best[r]) ? rk : best[r];
      u64 ck = cb | (unsigned)(r0 + r);
      ckey = (ck < ckey) ? ck : ckey;
    }
    u64 curv = g_colMin[0][c];  // stale reads only ever too-high: safe filter
    if (ckey < curv) atomicMin((unsigned long long*)&g_colMin[0][c], ckey);
  }

  // 4-wave block row-min reduce (8 rows), then global atomic merge
  {
    const int lane = tid & 63, wv = tid >> 6;
#pragma unroll
    for (int r = 0; r < 8; ++r) {
      u64 v = best[r];
#pragma unroll
      for (int d = 32; d > 0; d >>= 1) {
        u64 o = shfl_down_u64(v, d);
        v = (o < v) ? o : v;
      }
      if (lane == 0) s_part[r * 4 + wv] = v;
    }
    __syncthreads();
    if (tid < 8) {
      u64 mn = s_part[tid * 4];
#pragma unroll
      for (int w = 1; w < 4; ++w) {
        u64 o = s_part[tid * 4 + w];
        mn = (o < mn) ? o : mn;
      }
      u64 curv = g_rowMinR[0][r0 + tid];  // stale-read filter: safe
      if (mn < curv) atomicMin((unsigned long long*)&g_rowMinR[0][r0 + tid], mn);
    }
  }
  (void)y;
}

// ================= rounds >= 1: gather scan with TOP-2 row/col minima =======
// PROVEN round-15 kernel — unchanged. Column-split S + top-2 maintenance on
// both axes so k_match runs two mutual-min iterations per launch.
__global__ void __launch_bounds__(SNT, 2) k_scanN(int round) {
  if (g_done) return;
  const int cur = round & 1;
  const int nr = g_nr[cur], nc = g_nc[cur];
  const int tid = threadIdx.x, bid = blockIdx.x;

  for (int t = bid * SNT + tid; t < N; t += SNB * SNT) {
    g_colMin[cur ^ 1][t] = ~0ull;
    g_colMin2[cur ^ 1][t] = ~0ull;
    g_rowMinR[cur ^ 1][t] = ~0ull;
    g_rowMin2[cur ^ 1][t] = ~0ull;
  }

  const int ngroups = (nr + 15) >> 4;
  int lgS = 0;
  while (lgS < 4 && (ngroups << (lgS + 1)) <= SNB) ++lgS;
  const int S = 1 << lgS;
  if (bid >= (ngroups << lgS)) return;
  const int g = bid >> lgS;          // row group
  const int s = bid & (S - 1);       // column split index

  __shared__ u64 s_cp1[4096];
  __shared__ u64 s_cp2[4096];
  __shared__ u64 s_p1[128 + 16];
  __shared__ u64 s_p2[128 + 16];
  __shared__ int s_irow[16];

  const int r0 = g << 4;
  const int rows = min(16, nr - r0);
  if (tid < 16) {
    int rr = (tid < rows) ? (r0 + tid) : r0;
    s_irow[tid] = g_freeRows[cur][rr];
  }
  const int cstart = (s << 9) + tid;     // s*512 + tid
  const int cstep = S << 9;              // S*512
  for (int c = cstart; c < nc; c += cstep) { s_cp1[c] = ~0ull; s_cp2[c] = ~0ull; }
  __syncthreads();

  int ir[16];
#pragma unroll
  for (int r = 0; r < 16; ++r) ir[r] = s_irow[r];
  u64 b1[16], b2[16];
#pragma unroll
  for (int r = 0; r < 16; ++r) { b1[r] = ~0ull; b2[r] = ~0ull; }

  for (int c = cstart; c < nc; c += cstep) {
    const int j = g_freeCols[cur][c];
    u64 c1 = s_cp1[c], c2 = s_cp2[c];
#pragma unroll
    for (int r = 0; r < 16; ++r) {
      if (r < rows) {
        float cost = g_C[(size_t)ir[r] * N + j];
        u64 cb = ((u64)__float_as_uint(cost)) << 32;
        u64 rk = cb | (unsigned)j;
        if (rk < b1[r]) { b2[r] = b1[r]; b1[r] = rk; }
        else if (rk < b2[r]) b2[r] = rk;
        u64 ck = cb | (unsigned)ir[r];
        if (ck < c1) { c2 = c1; c1 = ck; }
        else if (ck < c2) c2 = ck;
      }
    }
    s_cp1[c] = c1; s_cp2[c] = c2;
  }

  // row-side top-2 block reduce + global merge
  {
    const int lane = tid & 63, wv = tid >> 6;
#pragma unroll
    for (int r = 0; r < 16; ++r) {
      if (r < rows) {
        u64 v1 = b1[r], v2 = b2[r];
#pragma unroll
        for (int d = 32; d > 0; d >>= 1) {
          u64 o1 = shfl_down_u64(v1, d);
          u64 o2 = shfl_down_u64(v2, d);
          u64 n1 = (v1 < o1) ? v1 : o1;
          u64 hi = (v1 < o1) ? o1 : v1;
          u64 lo = (v2 < o2) ? v2 : o2;
          v1 = n1;
          v2 = (hi < lo) ? hi : lo;
        }
        if (lane == 0) { s_p1[r * 8 + wv] = v1; s_p2[r * 8 + wv] = v2; }
      }
    }
    __syncthreads();
    if (tid < rows) {
      u64 m1 = s_p1[tid * 8], m2 = s_p2[tid * 8];
#pragma unroll
      for (int w = 1; w < 8; ++w) {
        u64 o1 = s_p1[tid * 8 + w], o2 = s_p2[tid * 8 + w];
        u64 n1 = (m1 < o1) ? m1 : o1;
        u64 hi = (m1 < o1) ? o1 : m1;
        u64 lo = (m2 < o2) ? m2 : o2;
        m1 = n1;
        m2 = (hi < lo) ? hi : lo;
      }
      const int i = s_irow[tid];
      insert2(&g_rowMinR[cur][i], &g_rowMin2[cur][i], m1);
      insert2(&g_rowMinR[cur][i], &g_rowMin2[cur][i], m2);
    }
  }

  // col-side global merge
  for (int c = cstart; c < nc; c += cstep) {
    u64 k1 = s_cp1[c];
    if (k1 != ~0ull) {
      const int j = g_freeCols[cur][c];
      insert2(&g_colMin[cur][j], &g_colMin2[cur][j], k1);
      insert2(&g_colMin[cur][j], &g_colMin2[cur][j], s_cp2[c]);
    }
  }
}

// ================= match: TWO mutual-min iterations + rebuild free lists ====
// PROVEN round-15 kernel — unchanged. Iter 1 = mutual-min; iter 2 uses
// top-2 candidates filtered by iter-1 matches; both sides evaluate
// identical predicates on identical global data -> agree without sync.
// Round 0: min2 buffers are ~0 sentinels -> iter-2 no-ops.
__global__ void __launch_bounds__(SNT) k_match(int round) {
  if (g_done) return;
  const int cur = round & 1, nxt = cur ^ 1;
  const int tid = threadIdx.x, bid = blockIdx.x;
  const int nr = g_nr[cur], nc = g_nc[cur];
  __shared__ int s_wc[8];
  __shared__ int s_base;

  const int lane = tid & 63, wv = tid >> 6;
  if (bid == 0) {  // rows
    if (tid == 0) s_base = 0;
    __syncthreads();
    for (int start = 0; start < nr; start += SNT) {
      int r = start + tid;
      int keep = 0; int iv = -1;
      if (r < nr) {
        int i = g_freeRows[cur][r];
        iv = i;
        u64 rm1 = g_rowMinR[cur][i];
        int j1 = LO32(rm1);
        int i1 = LO32(g_colMin[cur][j1]);
        if (i1 == i) {
          g_rowMatch[i] = j1;  // iter 1
        } else {
          // iter 2: candidate col for row i
          int jc = -1;
          bool j1gone = (LO32(g_rowMinR[cur][i1]) == j1);  // j1 matched iter1
          if (!j1gone) jc = j1;
          else {
            u64 rm2 = g_rowMin2[cur][i];
            if (rm2 != ~0ull) {
              int j2 = LO32(rm2);
              int i2 = LO32(g_colMin[cur][j2]);
              if (LO32(g_rowMinR[cur][i2]) != j2) jc = j2;  // j2 free
            }
          }
          int rc = -1;
          if (jc >= 0) {  // col jc's current min free row
            int r1 = LO32(g_colMin[cur][jc]);
            int jr1 = LO32(g_rowMinR[cur][r1]);
            bool r1m = (LO32(g_colMin[cur][jr1]) == r1);  // r1 matched iter1
            if (!r1m) rc = r1;
            else {
              u64 cm2 = g_colMin2[cur][jc];
              if (cm2 != ~0ull) {
                int r2 = LO32(cm2);
                int jr2 = LO32(g_rowMinR[cur][r2]);
                if (LO32(g_colMin[cur][jr2]) != r2) rc = r2;
              }
            }
          }
          if (jc >= 0 && rc == i) g_rowMatch[i] = jc;  // iter 2 match
          else keep = 1;
        }
      }
      u64 bm = __ballot(keep);
      int pre = __popcll(bm & ((1ull << lane) - 1ull));
      if (lane == 0) s_wc[wv] = __popcll(bm);
      __syncthreads();
      int off = 0, tot = 0;
#pragma unroll
      for (int w = 0; w < 8; ++w) { off += (w < wv) ? s_wc[w] : 0; tot += s_wc[w]; }
      if (keep) g_freeRows[nxt][s_base + off + pre] = iv;
      __syncthreads();
      if (tid == 0) s_base += tot;
      __syncthreads();
    }
    if (tid == 0) {
      int nnr = s_base;
      g_nr[nxt] = nnr;
      if (nnr <= TTHRESH || nnr >= nr) { g_finalCur = nxt; g_done = 1; }
    }
  } else {  // cols
    if (tid == 0) s_base = 0;
    __syncthreads();
    for (int start = 0; start < nc; start += SNT) {
      int c = start + tid;
      int keep = 0; int jv = -1;
      if (c < nc) {
        int j = g_freeCols[cur][c];
        jv = j;
        u64 cm1 = g_colMin[cur][j];
        int i1 = LO32(cm1);
        if (LO32(g_rowMinR[cur][i1]) == j) {
          // matched iter 1
        } else {
          // j free after iter1; compute its current min free row rc
          int rc = -1;
          {
            int r1 = i1;
            int jr1 = LO32(g_rowMinR[cur][r1]);
            bool r1m = (LO32(g_colMin[cur][jr1]) == r1);
            if (!r1m) rc = r1;
            else {
              u64 cm2 = g_colMin2[cur][j];
              if (cm2 != ~0ull) {
                int r2 = LO32(cm2);
                int jr2 = LO32(g_rowMinR[cur][r2]);
                if (LO32(g_colMin[cur][jr2]) != r2) rc = r2;
              }
            }
          }
          int jc = -1;
          if (rc >= 0) {  // rc's current best free col
            int jA = LO32(g_rowMinR[cur][rc]);
            int iA = LO32(g_colMin[cur][jA]);
            bool jAgone = (LO32(g_rowMinR[cur][iA]) == jA);
            if (!jAgone) jc = jA;
            else {
              u64 rm2 = g_rowMin2[cur][rc];
              if (rm2 != ~0ull) {
                int jB = LO32(rm2);
                int iB = LO32(g_colMin[cur][jB]);
                if (LO32(g_rowMinR[cur][iB]) != jB) jc = jB;
              }
            }
          }
          if (!(rc >= 0 && jc == j)) keep = 1;  // else matched iter 2
        }
      }
      u64 bm = __ballot(keep);
      int pre = __popcll(bm & ((1ull << lane) - 1ull));
      if (lane == 0) s_wc[wv] = __popcll(bm);
      __syncthreads();
      int off = 0, tot = 0;
#pragma unroll
      for (int w = 0; w < 8; ++w) { off += (w < wv) ? s_wc[w] : 0; tot += s_wc[w]; }
      if (keep) g_freeCols[nxt][s_base + off + pre] = jv;
      __syncthreads();
      if (tid == 0) s_base += tot;
      __syncthreads();
    }
    if (tid == 0) g_nc[nxt] = s_base;
  }
}

// ================= gather dense tail submatrix (whole grid) =================
// PROVEN round-5 kernel — unchanged.
__global__ void __launch_bounds__(SNT) k_gather() {
  const int fc = g_finalCur;
  const int mr = g_nr[fc], mc = g_nc[fc];
  if (mr <= 0 || mr > TCAP || mc <= 0 || mc > TCAP) return;
  const int tid = threadIdx.x, bid = blockIdx.x;
  for (int rr = bid; rr < mr; rr += SNB) {
    const int irow = g_freeRows[fc][rr];
    const float* src = g_C + (size_t)irow * N;
    float* dst = g_tailC + (size_t)rr * TCAP;
    for (int c = tid; c < mc; c += SNT) {
      dst[c] = src[g_freeCols[fc][c]];
    }
  }
}

// ================= tail: one block, dense matrix, per-wave rows =================
// PROVEN round-5 kernel — unchanged.
__global__ void __launch_bounds__(1024, 1) k_tail(int* __restrict__ out) {
  __shared__ int s_rpos[2][TCAP], s_cpos[2][TCAP];
  __shared__ int s_rbest[TCAP];
  __shared__ u64 s_cmin[TCAP];
  __shared__ int s_wc[16];
  const int tid = threadIdx.x;
  const int lane = tid & 63, wv = tid >> 6;

  const int fc = g_finalCur;
  int mr = g_nr[fc], mc = g_nc[fc];
  if (mr < 0 || mr > TCAP || mc < 0 || mc > TCAP) mr = 0;  // bail loudly (validation fails)
  for (int t = tid; t < mr; t += 1024) s_rpos[0][t] = t;
  for (int t = tid; t < mc; t += 1024) s_cpos[0][t] = t;
  __syncthreads();

  int tcur = 0;
  for (int round = 0; round < 2048 && mr > 0; ++round) {
    // ---- phase A: row bests, one row per wave ----
    const int nit = (mc + 63) >> 6;
    int cpv[16];
#pragma unroll
    for (int k = 0; k < 16; ++k) {
      int ci = (k << 6) + lane;
      cpv[k] = (k < nit && ci < mc) ? s_cpos[tcur][ci] : 0;
    }
    for (int rr = wv; rr < mr; rr += 16) {
      const int rp = s_rpos[tcur][rr];
      const float* rowp = g_tailC + (size_t)rp * TCAP;
      u64 best = ~0ull;
#pragma unroll
      for (int k = 0; k < 16; ++k) {
        if (k < nit) {
          int ci = (k << 6) + lane;
          if (ci < mc) {
            float cost = rowp[cpv[k]];
            u64 key = (((u64)__float_as_uint(cost)) << 32) | (unsigned)ci;  // col position
            best = (key < best) ? key : best;
          }
        }
      }
#pragma unroll
      for (int d = 32; d > 0; d >>= 1) {
        u64 o = shfl_down_u64(best, d);
        best = (o < best) ? o : best;
      }
      if (lane == 0) s_rbest[rr] = (int)(best & 0xffffffffull);
    }
    __syncthreads();
    // ---- phase B: col mins, one col per thread (mc <= 1024 = blockDim) ----
    if (tid < mc) {
      const int cp = s_cpos[tcur][tid];
      const float* colp = g_tailC + cp;
      u64 best = ~0ull;
      int r = 0;
      for (; r + 4 <= mr; r += 4) {
#pragma unroll
        for (int q = 0; q < 4; ++q) {
          int rp = s_rpos[tcur][r + q];
          float cost = colp[(size_t)rp * TCAP];
          u64 key = (((u64)__float_as_uint(cost)) << 32) | (unsigned)(r + q);  // row position
          best = (key < best) ? key : best;
        }
      }
      for (; r < mr; ++r) {
        int rp = s_rpos[tcur][r];
        float cost = colp[(size_t)rp * TCAP];
        u64 key = (((u64)__float_as_uint(cost)) << 32) | (unsigned)r;
        best = (key < best) ? key : best;
      }
      s_cmin[tid] = best;
    }
    __syncthreads();
    // ---- match rows + compact ----
    int keep = 0;
    if (tid < mr) {
      int q = s_rbest[tid];
      if ((int)(unsigned)(s_cmin[q] & 0xffffffffull) == tid) {
        g_rowMatch[g_freeRows[fc][s_rpos[tcur][tid]]] = g_freeCols[fc][s_cpos[tcur][q]];
      } else keep = 1;
    }
    u64 bm = __ballot(keep);
    int pre = __popcll(bm & ((1ull << lane) - 1ull));
    if (lane == 0) s_wc[wv] = __popcll(bm);
    __syncthreads();
    int off = 0, tot = 0;
#pragma unroll
    for (int w = 0; w < 16; ++w) { off += (w < wv) ? s_wc[w] : 0; tot += s_wc[w]; }
    if (keep) s_rpos[tcur ^ 1][off + pre] = s_rpos[tcur][tid];
    int newmr = tot;
    __syncthreads();
    // ---- compact cols ----
    int keepc = 0;
    if (tid < mc) {
      int r2 = (int)(unsigned)(s_cmin[tid] & 0xffffffffull);
      if (s_rbest[r2] != tid) keepc = 1;
    }
    u64 bm2 = __ballot(keepc);
    int pre2 = __popcll(bm2 & ((1ull << lane) - 1ull));
    if (lane == 0) s_wc[wv] = __popcll(bm2);
    __syncthreads();
    int off2 = 0, tot2 = 0;
#pragma unroll
    for (int w = 0; w < 16; ++w) { off2 += (w < wv) ? s_wc[w] : 0; tot2 += s_wc[w]; }
    if (keepc) s_cpos[tcur ^ 1][off2 + pre2] = s_cpos[tcur][tid];
    __syncthreads();
    if (newmr >= mr) break;  // safety (cannot happen mathematically)
    mr = newmr; mc = tot2; tcur ^= 1;
  }
  __syncthreads();
  for (int i = tid; i < N; i += 1024) out[i] = g_rowMatch[i];
}

extern "C" void kernel_launch(void* const* d_in, const int* in_sizes, int n_in,
                              void* d_out, int out_size, void* d_ws, size_t ws_size,
                              hipStream_t stream) {
  const float* x = (const float*)d_in[0];
  const float* y = (const float*)d_in[1];
  int* out = (int*)d_out;
  k_init<<<16, 256, 0, stream>>>(x, y);
  k_scan0<<<S0B, S0T, 0, stream>>>(x, y);
  k_match<<<2, SNT, 0, stream>>>(0);
  for (int r = 1; r <= RPAIRS; ++r) {
    k_scanN<<<SNB, SNT, 0, stream>>>(r);
    k_match<<<2, SNT, 0, stream>>>(r);
  }
  k_gather<<<SNB, SNT, 0, stream>>>();
  k_tail<<<1, 1024, 0, stream>>>(out);
  (void)in_sizes; (void)n_in; (void)out_size; (void)d_ws; (void)ws_size;
}

// Round 17
// 657.229 us; speedup vs baseline: 1.2981x; 1.2981x over previous
//
#include <hip/hip_runtime.h>

#define N 4096
#define D 64
#define TCAP 1024
#define SNB 256
#define SNT 512
#define S0B 1024
#define S0T 512
#define RPAIRS 9

typedef unsigned long long u64;
#define LO32(k) ((int)(unsigned)((k) & 0xffffffffull))

// ---- persistent device state ----
__device__ float g_C[(size_t)N * (size_t)N];   // 64 MB cost matrix
__device__ float g_tailC[(size_t)TCAP * TCAP]; // 4 MB dense tail matrix
__device__ float4 g_yT[N * 16];                // y transposed: [kc][row] float4 slices (1 MB)
__device__ float g_x2[N], g_y2[N];
__device__ int   g_rowMatch[N];
__device__ int   g_freeRows[2][N];
__device__ int   g_freeCols[2][N];
// per-round row/col min keys, double-buffered by round parity.
// rowMinR/colMin = 1st min; rowMin2/colMin2 = 2nd min (distinct col/row).
// [parity 0] is also round-0's buffer (scan0 writes 1st-min only; 2nd-min
// stays ~0 sentinel -> match(0)'s iter-2 degrades to a no-op).
__device__ u64   g_rowMinR[2][N];
__device__ u64   g_rowMin2[2][N];
__device__ u64   g_colMin[2][N];
__device__ u64   g_colMin2[2][N];
__device__ int   g_nr[2], g_nc[2];   // accumulated by k_match via atomicAdd
__device__ int   g_finalCur;

__device__ inline u64 shfl_down_u64(u64 v, int d) {
  unsigned lo = (unsigned)(v & 0xffffffffull);
  unsigned hi = (unsigned)(v >> 32);
  lo = __shfl_down(lo, d, 64);
  hi = __shfl_down(hi, d, 64);
  return ((u64)hi << 32) | (u64)lo;
}

// constant-index float4-array element access (folds to a register after unroll)
__device__ __forceinline__ float f4e(const float4* a, int e) {
  float4 v = a[e >> 2];
  switch (e & 3) {
    case 0: return v.x;
    case 1: return v.y;
    case 2: return v.z;
    default: return v.w;
  }
}

// two-cell atomic top-2 insert: m1 = global min, m2 = global 2nd-min.
// Standard displacement trick; correct for distinct-key streams.
__device__ __forceinline__ void insert2(u64* m1, u64* m2, u64 k) {
  if (k == ~0ull) return;
  u64 old = atomicMin((unsigned long long*)m1, k);
  u64 loser = (k < old) ? old : k;
  if (loser != ~0ull) atomicMin((unsigned long long*)m2, loser);
}

// ================= init: x2/y2 + y-transpose + state reset =================
__global__ void __launch_bounds__(256) k_init(const float* __restrict__ x,
                                              const float* __restrict__ y) {
  const int i = blockIdx.x * 256 + threadIdx.x;  // grid = 16 blocks -> 4096
  // numpy pairwise_sum order for n=64: 8 accumulators, then
  // ((r0+r1)+(r2+r3)) + ((r4+r5)+(r6+r7)). No FMA contraction.
  const float4* xr4 = reinterpret_cast<const float4*>(x + (size_t)i * D);
  const float4* yr4 = reinterpret_cast<const float4*>(y + (size_t)i * D);

  {  // x pass
    float4 xv[16];
#pragma unroll
    for (int k = 0; k < 16; ++k) xv[k] = xr4[k];
    float qx[8];
#pragma unroll
    for (int j = 0; j < 8; ++j) {
      float v = f4e(xv, j);
      qx[j] = __fmul_rn(v, v);
    }
#pragma unroll
    for (int m = 8; m < D; m += 8) {
#pragma unroll
      for (int j = 0; j < 8; ++j) {
        float v = f4e(xv, m + j);
        qx[j] = __fadd_rn(qx[j], __fmul_rn(v, v));
      }
    }
    g_x2[i] = __fadd_rn(__fadd_rn(__fadd_rn(qx[0], qx[1]), __fadd_rn(qx[2], qx[3])),
                        __fadd_rn(__fadd_rn(qx[4], qx[5]), __fadd_rn(qx[6], qx[7])));
  }
  {  // y pass + transpose store
    float4 yv[16];
#pragma unroll
    for (int k = 0; k < 16; ++k) yv[k] = yr4[k];
    float qy[8];
#pragma unroll
    for (int j = 0; j < 8; ++j) {
      float w = f4e(yv, j);
      qy[j] = __fmul_rn(w, w);
    }
#pragma unroll
    for (int m = 8; m < D; m += 8) {
#pragma unroll
      for (int j = 0; j < 8; ++j) {
        float w = f4e(yv, m + j);
        qy[j] = __fadd_rn(qy[j], __fmul_rn(w, w));
      }
    }
    g_y2[i] = __fadd_rn(__fadd_rn(__fadd_rn(qy[0], qy[1]), __fadd_rn(qy[2], qy[3])),
                        __fadd_rn(__fadd_rn(qy[4], qy[5]), __fadd_rn(qy[6], qy[7])));
    // yT[kc][row]: lane-consecutive i -> fully coalesced 16B stores per kc
#pragma unroll
    for (int k = 0; k < 16; ++k) g_yT[(k << 12) + i] = yv[k];
  }

  g_rowMatch[i] = -1;
  g_freeRows[0][i] = i;
  g_freeCols[0][i] = i;
  g_rowMinR[0][i] = ~0ull;
  g_rowMinR[1][i] = ~0ull;
  g_rowMin2[0][i] = ~0ull;
  g_rowMin2[1][i] = ~0ull;
  g_colMin[0][i] = ~0ull;
  g_colMin[1][i] = ~0ull;
  g_colMin2[0][i] = ~0ull;
  g_colMin2[1][i] = ~0ull;
  if (i == 0) {
    g_nr[0] = N; g_nc[0] = N; g_nr[1] = 0; g_nc[1] = 0;
    g_finalCur = ((RPAIRS & 1) ^ 1);  // static final parity (= match(RPAIRS)'s nxt)
  }
}

// ================= round 0: fused cost + C store + row/col minima =================
// PROVEN round-13/15 kernel (138us, 124 VGPR, no spill) — REVERTED VERBATIM
// (round-16's 256-thread 4-quarter geometry regressed; 6th regalloc burn).
// 1024 blocks = 512 row-groups (8 rows) x 2 column halves. acc[8][4],
// wave-uniform x float4 loads -> SGPRs, yT lane-contiguous loads, plain C
// stores, bare __launch_bounds__ (",4" variant spilled historically).
// Per-(r,c) fmaf chain order: kc ascending, x/y/z/w -> bit-exact costs.
__global__ void __launch_bounds__(S0T) k_scan0(const float* __restrict__ x,
                                               const float* __restrict__ y) {
  __shared__ u64 s_part[64 + 8];
  const int tid = threadIdx.x;
  const int r0 = (blockIdx.x >> 1) << 3;   // 512 row-groups x 8 rows
  const int h = blockIdx.x & 1;            // column half (2048 cols)

  float x2r[8];
#pragma unroll
  for (int r = 0; r < 8; ++r) x2r[r] = g_x2[r0 + r];
  u64 best[8];
#pragma unroll
  for (int r = 0; r < 8; ++r) best[r] = ~0ull;

  const int c0 = tid + (h << 11);  // cols c0 + 512*k, k=0..3
  float acc[8][4];
#pragma unroll
  for (int r = 0; r < 8; ++r)
#pragma unroll
    for (int k = 0; k < 4; ++k) acc[r][k] = 0.0f;

#pragma unroll
  for (int kc = 0; kc < 16; ++kc) {
    const float4* ytk = g_yT + (kc << 12);
    float4 yv0 = ytk[c0];
    float4 yv1 = ytk[c0 + 512];
    float4 yv2 = ytk[c0 + 1024];
    float4 yv3 = ytk[c0 + 1536];
#pragma unroll
    for (int r = 0; r < 8; ++r) {
      float4 xv = reinterpret_cast<const float4*>(x + (size_t)(r0 + r) * D)[kc];  // wave-uniform -> SGPR
      acc[r][0] = fmaf(xv.x, yv0.x, acc[r][0]);
      acc[r][0] = fmaf(xv.y, yv0.y, acc[r][0]);
      acc[r][0] = fmaf(xv.z, yv0.z, acc[r][0]);
      acc[r][0] = fmaf(xv.w, yv0.w, acc[r][0]);
      acc[r][1] = fmaf(xv.x, yv1.x, acc[r][1]);
      acc[r][1] = fmaf(xv.y, yv1.y, acc[r][1]);
      acc[r][1] = fmaf(xv.z, yv1.z, acc[r][1]);
      acc[r][1] = fmaf(xv.w, yv1.w, acc[r][1]);
      acc[r][2] = fmaf(xv.x, yv2.x, acc[r][2]);
      acc[r][2] = fmaf(xv.y, yv2.y, acc[r][2]);
      acc[r][2] = fmaf(xv.z, yv2.z, acc[r][2]);
      acc[r][2] = fmaf(xv.w, yv2.w, acc[r][2]);
      acc[r][3] = fmaf(xv.x, yv3.x, acc[r][3]);
      acc[r][3] = fmaf(xv.y, yv3.y, acc[r][3]);
      acc[r][3] = fmaf(xv.z, yv3.z, acc[r][3]);
      acc[r][3] = fmaf(xv.w, yv3.w, acc[r][3]);
    }
  }

#pragma unroll
  for (int k = 0; k < 4; ++k) {
    const int c = c0 + (k << 9);
    const float y2j = g_y2[c];
    u64 ckey = ~0ull;
#pragma unroll
    for (int r = 0; r < 8; ++r) {
      float t = __fadd_rn(x2r[r], y2j);
      float sq = __fsub_rn(t, __fmul_rn(2.0f, acc[r][k]));
      sq = fmaxf(sq, 0.0f);
      float cost = __fsqrt_rn(sq);
      g_C[(size_t)(r0 + r) * N + c] = cost;
      u64 cb = ((u64)__float_as_uint(cost)) << 32;
      u64 rk = cb | (unsigned)c;
      best[r] = (rk < best[r]) ? rk : best[r];
      u64 ck = cb | (unsigned)(r0 + r);
      ckey = (ck < ckey) ? ck : ckey;
    }
    u64 curv = g_colMin[0][c];  // stale reads only ever too-high: safe filter
    if (ckey < curv) atomicMin((unsigned long long*)&g_colMin[0][c], ckey);
  }

  // 8-wave block row-min reduce (8 rows), then global atomic merge
  {
    const int lane = tid & 63, wv = tid >> 6;
#pragma unroll
    for (int r = 0; r < 8; ++r) {
      u64 v = best[r];
#pragma unroll
      for (int d = 32; d > 0; d >>= 1) {
        u64 o = shfl_down_u64(v, d);
        v = (o < v) ? o : v;
      }
      if (lane == 0) s_part[r * 8 + wv] = v;
    }
    __syncthreads();
    if (tid < 8) {
      u64 mn = s_part[tid * 8];
#pragma unroll
      for (int w = 1; w < 8; ++w) {
        u64 o = s_part[tid * 8 + w];
        mn = (o < mn) ? o : mn;
      }
      u64 curv = g_rowMinR[0][r0 + tid];  // stale-read filter: safe
      if (mn < curv) atomicMin((unsigned long long*)&g_rowMinR[0][r0 + tid], mn);
    }
  }
  (void)y;
}

// ================= rounds >= 1: gather scan with TOP-2 row/col minima =======
// PROVEN round-15 kernel; done-check removed (done provably never fired:
// measured removal rate ~0.72/launch, 157 rows after 9 rounds > TTHRESH).
// Preamble additionally zeroes g_nr/g_nc[cur^1] so k_match can accumulate
// counts with atomicAdd (order-free parallel compaction).
__global__ void __launch_bounds__(SNT, 2) k_scanN(int round) {
  const int cur = round & 1;
  const int nr = g_nr[cur], nc = g_nc[cur];
  const int tid = threadIdx.x, bid = blockIdx.x;

  if (bid == 0 && tid == 0) { g_nr[cur ^ 1] = 0; g_nc[cur ^ 1] = 0; }
  for (int t = bid * SNT + tid; t < N; t += SNB * SNT) {
    g_colMin[cur ^ 1][t] = ~0ull;
    g_colMin2[cur ^ 1][t] = ~0ull;
    g_rowMinR[cur ^ 1][t] = ~0ull;
    g_rowMin2[cur ^ 1][t] = ~0ull;
  }

  const int ngroups = (nr + 15) >> 4;
  int lgS = 0;
  while (lgS < 4 && (ngroups << (lgS + 1)) <= SNB) ++lgS;
  const int S = 1 << lgS;
  if (bid >= (ngroups << lgS)) return;
  const int g = bid >> lgS;          // row group
  const int s = bid & (S - 1);       // column split index

  __shared__ u64 s_cp1[4096];
  __shared__ u64 s_cp2[4096];
  __shared__ u64 s_p1[128 + 16];
  __shared__ u64 s_p2[128 + 16];
  __shared__ int s_irow[16];

  const int r0 = g << 4;
  const int rows = min(16, nr - r0);
  if (tid < 16) {
    int rr = (tid < rows) ? (r0 + tid) : r0;
    s_irow[tid] = g_freeRows[cur][rr];
  }
  const int cstart = (s << 9) + tid;     // s*512 + tid
  const int cstep = S << 9;              // S*512
  for (int c = cstart; c < nc; c += cstep) { s_cp1[c] = ~0ull; s_cp2[c] = ~0ull; }
  __syncthreads();

  int ir[16];
#pragma unroll
  for (int r = 0; r < 16; ++r) ir[r] = s_irow[r];
  u64 b1[16], b2[16];
#pragma unroll
  for (int r = 0; r < 16; ++r) { b1[r] = ~0ull; b2[r] = ~0ull; }

  for (int c = cstart; c < nc; c += cstep) {
    const int j = g_freeCols[cur][c];
    u64 c1 = s_cp1[c], c2 = s_cp2[c];
#pragma unroll
    for (int r = 0; r < 16; ++r) {
      if (r < rows) {
        float cost = g_C[(size_t)ir[r] * N + j];
        u64 cb = ((u64)__float_as_uint(cost)) << 32;
        u64 rk = cb | (unsigned)j;
        if (rk < b1[r]) { b2[r] = b1[r]; b1[r] = rk; }
        else if (rk < b2[r]) b2[r] = rk;
        u64 ck = cb | (unsigned)ir[r];
        if (ck < c1) { c2 = c1; c1 = ck; }
        else if (ck < c2) c2 = ck;
      }
    }
    s_cp1[c] = c1; s_cp2[c] = c2;
  }

  // row-side top-2 block reduce + global merge
  {
    const int lane = tid & 63, wv = tid >> 6;
#pragma unroll
    for (int r = 0; r < 16; ++r) {
      if (r < rows) {
        u64 v1 = b1[r], v2 = b2[r];
#pragma unroll
        for (int d = 32; d > 0; d >>= 1) {
          u64 o1 = shfl_down_u64(v1, d);
          u64 o2 = shfl_down_u64(v2, d);
          u64 n1 = (v1 < o1) ? v1 : o1;
          u64 hi = (v1 < o1) ? o1 : v1;
          u64 lo = (v2 < o2) ? v2 : o2;
          v1 = n1;
          v2 = (hi < lo) ? hi : lo;
        }
        if (lane == 0) { s_p1[r * 8 + wv] = v1; s_p2[r * 8 + wv] = v2; }
      }
    }
    __syncthreads();
    if (tid < rows) {
      u64 m1 = s_p1[tid * 8], m2 = s_p2[tid * 8];
#pragma unroll
      for (int w = 1; w < 8; ++w) {
        u64 o1 = s_p1[tid * 8 + w], o2 = s_p2[tid * 8 + w];
        u64 n1 = (m1 < o1) ? m1 : o1;
        u64 hi = (m1 < o1) ? o1 : m1;
        u64 lo = (m2 < o2) ? m2 : o2;
        m1 = n1;
        m2 = (hi < lo) ? hi : lo;
      }
      const int i = s_irow[tid];
      insert2(&g_rowMinR[cur][i], &g_rowMin2[cur][i], m1);
      insert2(&g_rowMinR[cur][i], &g_rowMin2[cur][i], m2);
    }
  }

  // col-side global merge
  for (int c = cstart; c < nc; c += cstep) {
    u64 k1 = s_cp1[c];
    if (k1 != ~0ull) {
      const int j = g_freeCols[cur][c];
      insert2(&g_colMin[cur][j], &g_colMin2[cur][j], k1);
      insert2(&g_colMin[cur][j], &g_colMin2[cur][j], s_cp2[c]);
    }
  }
}

// ================= match: two mutual-min iterations, PARALLEL compaction ====
// PROVEN round-15 predicates (iter1 mutual-min + iter2 top-2 chain),
// restructured: 256 blocks, ONE THREAD PER LIST ENTRY (blocks 0-127 rows,
// 128-255 cols; 65536 threads >= nr,nc). Compaction is ORDER-FREE (all
// minima are global atomics keyed on (cost,index); list order only affects
// scanN grouping, not results): wave ballot + per-wave atomicAdd segment
// reservation directly into g_nr/g_nc[nxt] (zeroed by scanN's preamble;
// k_init zeroes parity 1 for match(0)). Replaces the 2-block serial walk
// (match0 ~60us latency-bound -> ~8us).
__global__ void __launch_bounds__(SNT) k_match(int round) {
  const int cur = round & 1, nxt = cur ^ 1;
  const int tid = threadIdx.x, bid = blockIdx.x;
  const int lane = tid & 63;

  if (bid < 128) {  // rows
    const int nr = g_nr[cur];
    int r = bid * SNT + tid;
    int keep = 0; int iv = -1;
    if (r < nr) {
      int i = g_freeRows[cur][r];
      iv = i;
      u64 rm1 = g_rowMinR[cur][i];
      int j1 = LO32(rm1);
      int i1 = LO32(g_colMin[cur][j1]);
      if (i1 == i) {
        g_rowMatch[i] = j1;  // iter 1
      } else {
        // iter 2: candidate col for row i
        int jc = -1;
        bool j1gone = (LO32(g_rowMinR[cur][i1]) == j1);  // j1 matched iter1
        if (!j1gone) jc = j1;
        else {
          u64 rm2 = g_rowMin2[cur][i];
          if (rm2 != ~0ull) {
            int j2 = LO32(rm2);
            int i2 = LO32(g_colMin[cur][j2]);
            if (LO32(g_rowMinR[cur][i2]) != j2) jc = j2;  // j2 free
          }
        }
        int rc = -1;
        if (jc >= 0) {  // col jc's current min free row
          int r1 = LO32(g_colMin[cur][jc]);
          int jr1 = LO32(g_rowMinR[cur][r1]);
          bool r1m = (LO32(g_colMin[cur][jr1]) == r1);  // r1 matched iter1
          if (!r1m) rc = r1;
          else {
            u64 cm2 = g_colMin2[cur][jc];
            if (cm2 != ~0ull) {
              int r2 = LO32(cm2);
              int jr2 = LO32(g_rowMinR[cur][r2]);
              if (LO32(g_colMin[cur][jr2]) != r2) rc = r2;
            }
          }
        }
        if (jc >= 0 && rc == i) g_rowMatch[i] = jc;  // iter 2 match
        else keep = 1;
      }
    }
    u64 bm = __ballot(keep);
    int pre = __popcll(bm & ((1ull << lane) - 1ull));
    int cnt = __popcll(bm);
    int base = 0;
    if (lane == 0 && cnt) base = atomicAdd(&g_nr[nxt], cnt);
    base = __shfl(base, 0, 64);
    if (keep) g_freeRows[nxt][base + pre] = iv;
  } else {  // cols
    const int nc = g_nc[cur];
    int c = (bid - 128) * SNT + tid;
    int keep = 0; int jv = -1;
    if (c < nc) {
      int j = g_freeCols[cur][c];
      jv = j;
      u64 cm1 = g_colMin[cur][j];
      int i1 = LO32(cm1);
      if (LO32(g_rowMinR[cur][i1]) == j) {
        // matched iter 1
      } else {
        // j free after iter1; compute its current min free row rc
        int rc = -1;
        {
          int r1 = i1;
          int jr1 = LO32(g_rowMinR[cur][r1]);
          bool r1m = (LO32(g_colMin[cur][jr1]) == r1);
          if (!r1m) rc = r1;
          else {
            u64 cm2 = g_colMin2[cur][j];
            if (cm2 != ~0ull) {
              int r2 = LO32(cm2);
              int jr2 = LO32(g_rowMinR[cur][r2]);
              if (LO32(g_colMin[cur][jr2]) != r2) rc = r2;
            }
          }
        }
        int jc = -1;
        if (rc >= 0) {  // rc's current best free col
          int jA = LO32(g_rowMinR[cur][rc]);
          int iA = LO32(g_colMin[cur][jA]);
          bool jAgone = (LO32(g_rowMinR[cur][iA]) == jA);
          if (!jAgone) jc = jA;
          else {
            u64 rm2 = g_rowMin2[cur][rc];
            if (rm2 != ~0ull) {
              int jB = LO32(rm2);
              int iB = LO32(g_colMin[cur][jB]);
              if (LO32(g_rowMinR[cur][iB]) != jB) jc = jB;
            }
          }
        }
        if (!(rc >= 0 && jc == j)) keep = 1;  // else matched iter 2
      }
    }
    u64 bm = __ballot(keep);
    int pre = __popcll(bm & ((1ull << lane) - 1ull));
    int cnt = __popcll(bm);
    int base = 0;
    if (lane == 0 && cnt) base = atomicAdd(&g_nc[nxt], cnt);
    base = __shfl(base, 0, 64);
    if (keep) g_freeCols[nxt][base + pre] = jv;
  }
}

// ================= gather dense tail submatrix (whole grid) =================
// PROVEN round-5 kernel — unchanged.
__global__ void __launch_bounds__(SNT) k_gather() {
  const int fc = g_finalCur;
  const int mr = g_nr[fc], mc = g_nc[fc];
  if (mr <= 0 || mr > TCAP || mc <= 0 || mc > TCAP) return;
  const int tid = threadIdx.x, bid = blockIdx.x;
  for (int rr = bid; rr < mr; rr += SNB) {
    const int irow = g_freeRows[fc][rr];
    const float* src = g_C + (size_t)irow * N;
    float* dst = g_tailC + (size_t)rr * TCAP;
    for (int c = tid; c < mc; c += SNT) {
      dst[c] = src[g_freeCols[fc][c]];
    }
  }
}

// ================= tail: one block, dense matrix, per-wave rows =================
// PROVEN round-5 kernel — unchanged. Expected mr ~ 150-220 (rate 0.72^9);
// bails (validation fails visibly) if mr > TCAP.
__global__ void __launch_bounds__(1024, 1) k_tail(int* __restrict__ out) {
  __shared__ int s_rpos[2][TCAP], s_cpos[2][TCAP];
  __shared__ int s_rbest[TCAP];
  __shared__ u64 s_cmin[TCAP];
  __shared__ int s_wc[16];
  const int tid = threadIdx.x;
  const int lane = tid & 63, wv = tid >> 6;

  const int fc = g_finalCur;
  int mr = g_nr[fc], mc = g_nc[fc];
  if (mr < 0 || mr > TCAP || mc < 0 || mc > TCAP) mr = 0;  // bail loudly (validation fails)
  for (int t = tid; t < mr; t += 1024) s_rpos[0][t] = t;
  for (int t = tid; t < mc; t += 1024) s_cpos[0][t] = t;
  __syncthreads();

  int tcur = 0;
  for (int round = 0; round < 2048 && mr > 0; ++round) {
    // ---- phase A: row bests, one row per wave ----
    const int nit = (mc + 63) >> 6;
    int cpv[16];
#pragma unroll
    for (int k = 0; k < 16; ++k) {
      int ci = (k << 6) + lane;
      cpv[k] = (k < nit && ci < mc) ? s_cpos[tcur][ci] : 0;
    }
    for (int rr = wv; rr < mr; rr += 16) {
      const int rp = s_rpos[tcur][rr];
      const float* rowp = g_tailC + (size_t)rp * TCAP;
      u64 best = ~0ull;
#pragma unroll
      for (int k = 0; k < 16; ++k) {
        if (k < nit) {
          int ci = (k << 6) + lane;
          if (ci < mc) {
            float cost = rowp[cpv[k]];
            u64 key = (((u64)__float_as_uint(cost)) << 32) | (unsigned)ci;  // col position
            best = (key < best) ? key : best;
          }
        }
      }
#pragma unroll
      for (int d = 32; d > 0; d >>= 1) {
        u64 o = shfl_down_u64(best, d);
        best = (o < best) ? o : best;
      }
      if (lane == 0) s_rbest[rr] = (int)(best & 0xffffffffull);
    }
    __syncthreads();
    // ---- phase B: col mins, one col per thread (mc <= 1024 = blockDim) ----
    if (tid < mc) {
      const int cp = s_cpos[tcur][tid];
      const float* colp = g_tailC + cp;
      u64 best = ~0ull;
      int r = 0;
      for (; r + 4 <= mr; r += 4) {
#pragma unroll
        for (int q = 0; q < 4; ++q) {
          int rp = s_rpos[tcur][r + q];
          float cost = colp[(size_t)rp * TCAP];
          u64 key = (((u64)__float_as_uint(cost)) << 32) | (unsigned)(r + q);  // row position
          best = (key < best) ? key : best;
        }
      }
      for (; r < mr; ++r) {
        int rp = s_rpos[tcur][r];
        float cost = colp[(size_t)rp * TCAP];
        u64 key = (((u64)__float_as_uint(cost)) << 32) | (unsigned)r;
        best = (key < best) ? key : best;
      }
      s_cmin[tid] = best;
    }
    __syncthreads();
    // ---- match rows + compact ----
    int keep = 0;
    if (tid < mr) {
      int q = s_rbest[tid];
      if ((int)(unsigned)(s_cmin[q] & 0xffffffffull) == tid) {
        g_rowMatch[g_freeRows[fc][s_rpos[tcur][tid]]] = g_freeCols[fc][s_cpos[tcur][q]];
      } else keep = 1;
    }
    u64 bm = __ballot(keep);
    int pre = __popcll(bm & ((1ull << lane) - 1ull));
    if (lane == 0) s_wc[wv] = __popcll(bm);
    __syncthreads();
    int off = 0, tot = 0;
#pragma unroll
    for (int w = 0; w < 16; ++w) { off += (w < wv) ? s_wc[w] : 0; tot += s_wc[w]; }
    if (keep) s_rpos[tcur ^ 1][off + pre] = s_rpos[tcur][tid];
    int newmr = tot;
    __syncthreads();
    // ---- compact cols ----
    int keepc = 0;
    if (tid < mc) {
      int r2 = (int)(unsigned)(s_cmin[tid] & 0xffffffffull);
      if (s_rbest[r2] != tid) keepc = 1;
    }
    u64 bm2 = __ballot(keepc);
    int pre2 = __popcll(bm2 & ((1ull << lane) - 1ull));
    if (lane == 0) s_wc[wv] = __popcll(bm2);
    __syncthreads();
    int off2 = 0, tot2 = 0;
#pragma unroll
    for (int w = 0; w < 16; ++w) { off2 += (w < wv) ? s_wc[w] : 0; tot2 += s_wc[w]; }
    if (keepc) s_cpos[tcur ^ 1][off2 + pre2] = s_cpos[tcur][tid];
    __syncthreads();
    if (newmr >= mr) break;  // safety (cannot happen mathematically)
    mr = newmr; mc = tot2; tcur ^= 1;
  }
  __syncthreads();
  for (int i = tid; i < N; i += 1024) out[i] = g_rowMatch[i];
}

extern "C" void kernel_launch(void* const* d_in, const int* in_sizes, int n_in,
                              void* d_out, int out_size, void* d_ws, size_t ws_size,
                              hipStream_t stream) {
  const float* x = (const float*)d_in[0];
  const float* y = (const float*)d_in[1];
  int* out = (int*)d_out;
  k_init<<<16, 256, 0, stream>>>(x, y);
  k_scan0<<<S0B, S0T, 0, stream>>>(x, y);
  k_match<<<SNB, SNT, 0, stream>>>(0);
  for (int r = 1; r <= RPAIRS; ++r) {
    k_scanN<<<SNB, SNT, 0, stream>>>(r);
    k_match<<<SNB, SNT, 0, stream>>>(r);
  }
  k_gather<<<SNB, SNT, 0, stream>>>();
  k_tail<<<1, 1024, 0, stream>>>(out);
  (void)in_sizes; (void)n_in; (void)out_size; (void)d_ws; (void)ws_size;
}